// Round 1
// baseline (459.441 us; speedup 1.0000x reference)
//
#include <hip/hip_runtime.h>
#include <math.h>

// ---------------------------------------------------------------------------
// CrossAttention: B=8, N=M=2048, C=512, H=4, D=128, shared QKV weights (K==V)
//   q  = F1 @ W_qkv + b            (B,N,C)  -> bf16 ws
//   kv = F2 @ W_qkv + b            (B,M,C)  -> bf16 ws
//   x  = softmax(q kv^T / sqrt(C)) kv       -> bf16 ws
//   out= x @ W_proj + b_proj       (B,N,C)  fp32
// ---------------------------------------------------------------------------

typedef __attribute__((ext_vector_type(8))) short s16x8;   // 8 bf16 = 4 VGPR
typedef __attribute__((ext_vector_type(4))) float f32x4;   // MFMA acc
typedef __attribute__((ext_vector_type(4))) unsigned short u16x4;

#define C_DIM 512
#define HDIM  128
#define NROWS 16384           // B*N = B*M = 8*2048

__device__ __forceinline__ unsigned short f2bf(float f) {
    union { float f; unsigned u; } v; v.f = f;
    unsigned r = v.u + 0x7fffu + ((v.u >> 16) & 1u);   // RNE
    return (unsigned short)(r >> 16);
}

// ---------------------------------------------------------------------------
// GEMM: C[M x 512] = A[M x 512] @ W[512 x 512] + bias
// 128x128 block tile, BK=32, 4 waves in 2x2, each wave 64x64 (4x4 MFMA tiles)
// A_BF16: A is bf16 (ushort) else fp32.  OUT_BF16: write bf16 ws else fp32.
// ---------------------------------------------------------------------------
template <int A_BF16, int OUT_BF16>
__global__ __launch_bounds__(256, 2)
void gemm_bias_512(const void* __restrict__ Av,
                   const float* __restrict__ W,
                   const float* __restrict__ bias,
                   void* __restrict__ Cv) {
    __shared__ __align__(16) unsigned short As[128][32];  // [row][k]
    __shared__ __align__(16) unsigned short Bt[128][40];  // [n][k], pad 40

    const int tid  = threadIdx.x;
    const int wid  = tid >> 6;
    const int lane = tid & 63;
    const int lr   = lane & 15;
    const int quad = lane >> 4;
    const int wm   = wid >> 1;
    const int wn   = wid & 1;
    const int rowBase = blockIdx.y * 128;
    const int colBase = blockIdx.x * 128;

    f32x4 acc[4][4];
#pragma unroll
    for (int i = 0; i < 4; i++)
#pragma unroll
        for (int j = 0; j < 4; j++) acc[i][j] = (f32x4)0.0f;

    for (int kt = 0; kt < 16; kt++) {
        const int k0 = kt * 32;
        __syncthreads();
        // ---- stage A tile (128 x 32) as bf16, k-contiguous ----
        if (A_BF16) {
            const unsigned short* A = (const unsigned short*)Av;
#pragma unroll
            for (int i = 0; i < 2; i++) {
                int c = tid + 256 * i;          // 512 chunks of 8 bf16
                int row = c >> 2, q = c & 3;
                uint4 v = *(const uint4*)(A + (size_t)(rowBase + row) * C_DIM + k0 + q * 8);
                *(uint4*)&As[row][q * 8] = v;
            }
        } else {
            const float* A = (const float*)Av;
#pragma unroll
            for (int i = 0; i < 4; i++) {
                int c = tid + 256 * i;          // 1024 chunks of 4 fp32
                int row = c >> 3, q = c & 7;
                float4 v = *(const float4*)(A + (size_t)(rowBase + row) * C_DIM + k0 + q * 4);
                u16x4 o;
                o.x = f2bf(v.x); o.y = f2bf(v.y); o.z = f2bf(v.z); o.w = f2bf(v.w);
                *(u16x4*)&As[row][q * 4] = o;
            }
        }
        // ---- stage W tile transposed: Bt[n][k] (128 x 32) ----
#pragma unroll
        for (int i = 0; i < 4; i++) {
            int c = tid + 256 * i;              // 1024 chunks: n x (4 k)
            int n = c & 127, kc = c >> 7;       // kc in 0..7
            const float* wp = W + (size_t)(k0 + kc * 4) * C_DIM + colBase + n;
            float e0 = wp[0 * C_DIM];
            float e1 = wp[1 * C_DIM];
            float e2 = wp[2 * C_DIM];
            float e3 = wp[3 * C_DIM];
            u16x4 o;
            o.x = f2bf(e0); o.y = f2bf(e1); o.z = f2bf(e2); o.w = f2bf(e3);
            *(u16x4*)&Bt[n][kc * 4] = o;
        }
        __syncthreads();
        // ---- compute: 16 MFMAs ----
        s16x8 af[4], bf[4];
#pragma unroll
        for (int i = 0; i < 4; i++)
            af[i] = *(const s16x8*)&As[wm * 64 + i * 16 + lr][quad * 8];
#pragma unroll
        for (int j = 0; j < 4; j++)
            bf[j] = *(const s16x8*)&Bt[wn * 64 + j * 16 + lr][quad * 8];
#pragma unroll
        for (int i = 0; i < 4; i++)
#pragma unroll
            for (int j = 0; j < 4; j++)
                acc[i][j] = __builtin_amdgcn_mfma_f32_16x16x32_bf16(af[i], bf[j], acc[i][j], 0, 0, 0);
    }

    // ---- epilogue: C/D layout row = quad*4+r, col = lane&15 ----
    float bcol[4];
#pragma unroll
    for (int j = 0; j < 4; j++)
        bcol[j] = bias[colBase + wn * 64 + j * 16 + lr];
#pragma unroll
    for (int i = 0; i < 4; i++) {
#pragma unroll
        for (int j = 0; j < 4; j++) {
            int col = colBase + wn * 64 + j * 16 + lr;
#pragma unroll
            for (int r = 0; r < 4; r++) {
                int row = rowBase + wm * 64 + i * 16 + quad * 4 + r;
                float v = acc[i][j][r] + bcol[j];
                if (OUT_BF16)
                    ((unsigned short*)Cv)[(size_t)row * C_DIM + col] = f2bf(v);
                else
                    ((float*)Cv)[(size_t)row * C_DIM + col] = v;
            }
        }
    }
}

// ---------------------------------------------------------------------------
// Flash cross-attention. Grid (N/64, H, B), 256 thr. Wave w: 16 queries.
// Key tiles of 64. Kt[key][d] for QK^T b-frags, Vt[d][key] for PV b-frags.
// Online softmax in registers (per-row stats = per acc-reg r, quad-group
// shuffle reduce). P round-trips through per-wave LDS (C-layout -> A-layout).
// ---------------------------------------------------------------------------
__global__ __launch_bounds__(256, 3)
void cross_attn(const unsigned short* __restrict__ Q,
                const unsigned short* __restrict__ KV,
                unsigned short* __restrict__ X) {
    __shared__ __align__(16) unsigned short Kt[64][136];   // [key][d] +8 pad
    __shared__ __align__(16) unsigned short Vt[128][72];   // [d][key] +8 pad
    __shared__ __align__(16) unsigned short Pl[4][16][72]; // per-wave P[q][key]

    const int tid  = threadIdx.x;
    const int wid  = tid >> 6;
    const int lane = tid & 63;
    const int lr   = lane & 15;
    const int quad = lane >> 4;
    const int b    = blockIdx.z;
    const int h    = blockIdx.y;
    const int hoff = h * HDIM;
    const int qbase = blockIdx.x * 64 + wid * 16;
    const size_t qrow0  = (size_t)b * 2048 + qbase;
    const size_t kvrow0 = (size_t)b * 2048;

    // scale folded with log2(e): softmax in exp2 domain
    const float sl = 0.04419417382415922f * 1.4426950408889634f;

    // Q fragments: A[m=lr][k=kk*32+quad*8+j], contiguous in d -> registers
    s16x8 qf[4];
#pragma unroll
    for (int kk = 0; kk < 4; kk++)
        qf[kk] = *(const s16x8*)(Q + (qrow0 + lr) * C_DIM + hoff + kk * 32 + quad * 8);

    f32x4 O[8];
#pragma unroll
    for (int dt = 0; dt < 8; dt++) O[dt] = (f32x4)0.0f;
    float mrow[4], lrow[4];
#pragma unroll
    for (int r = 0; r < 4; r++) { mrow[r] = -1e30f; lrow[r] = 0.0f; }

    for (int kt = 0; kt < 32; kt++) {
        const int key0 = kt * 64;
        __syncthreads();
        // ---- stage KV tile: lane = key, conflict-free Vt transpose ----
#pragma unroll
        for (int i = 0; i < 4; i++) {
            int dc = wid + 4 * i;   // 16B chunk index along d
            uint4 v = *(const uint4*)(KV + (kvrow0 + key0 + lane) * C_DIM + hoff + dc * 8);
            *(uint4*)&Kt[lane][dc * 8] = v;
            const unsigned short* e = (const unsigned short*)&v;
#pragma unroll
            for (int t = 0; t < 8; t++) Vt[dc * 8 + t][lane] = e[t];
        }
        __syncthreads();

        // ---- S = Q K^T (16 queries x 64 keys), C-layout ----
        f32x4 s[4];
#pragma unroll
        for (int j = 0; j < 4; j++) s[j] = (f32x4)0.0f;
#pragma unroll
        for (int kk = 0; kk < 4; kk++) {
#pragma unroll
            for (int j = 0; j < 4; j++) {
                s16x8 kf = *(const s16x8*)&Kt[j * 16 + lr][kk * 32 + quad * 8];
                s[j] = __builtin_amdgcn_mfma_f32_16x16x32_bf16(qf[kk], kf, s[j], 0, 0, 0);
            }
        }

        // ---- online softmax: row = quad*4+r, cols across j & 16 lanes ----
        float t[4][4];   // [j][r], scaled logits then probabilities
#pragma unroll
        for (int j = 0; j < 4; j++)
#pragma unroll
            for (int r = 0; r < 4; r++) t[j][r] = s[j][r] * sl;

#pragma unroll
        for (int r = 0; r < 4; r++) {
            float m = t[0][r];
#pragma unroll
            for (int j = 1; j < 4; j++) m = fmaxf(m, t[j][r]);
#pragma unroll
            for (int off = 1; off < 16; off <<= 1)
                m = fmaxf(m, __shfl_xor(m, off));
            float mnew  = fmaxf(mrow[r], m);
            float alpha = exp2f(mrow[r] - mnew);
            float ls = 0.0f;
#pragma unroll
            for (int j = 0; j < 4; j++) {
                float p = exp2f(t[j][r] - mnew);
                t[j][r] = p;
                ls += p;
            }
#pragma unroll
            for (int off = 1; off < 16; off <<= 1)
                ls += __shfl_xor(ls, off);
            lrow[r] = lrow[r] * alpha + ls;
            mrow[r] = mnew;
#pragma unroll
            for (int dt = 0; dt < 8; dt++) O[dt][r] *= alpha;
        }

        // ---- P: C-layout -> A-layout via per-wave LDS (no barrier) ----
#pragma unroll
        for (int j = 0; j < 4; j++)
#pragma unroll
            for (int r = 0; r < 4; r++)
                Pl[wid][quad * 4 + r][j * 16 + lr] = f2bf(t[j][r]);

        // ---- O += P V ----
#pragma unroll
        for (int kk = 0; kk < 2; kk++) {
            s16x8 pa = *(const s16x8*)&Pl[wid][lr][kk * 32 + quad * 8];
#pragma unroll
            for (int dt = 0; dt < 8; dt++) {
                s16x8 vf = *(const s16x8*)&Vt[dt * 16 + lr][kk * 32 + quad * 8];
                O[dt] = __builtin_amdgcn_mfma_f32_16x16x32_bf16(pa, vf, O[dt], 0, 0, 0);
            }
        }
    }

    // ---- normalize + write X (bf16) ----
#pragma unroll
    for (int r = 0; r < 4; r++) {
        float inv = 1.0f / lrow[r];
#pragma unroll
        for (int dt = 0; dt < 8; dt++) {
            X[(qrow0 + quad * 4 + r) * C_DIM + hoff + dt * 16 + lr] =
                f2bf(O[dt][r] * inv);
        }
    }
}

// ---------------------------------------------------------------------------
extern "C" void kernel_launch(void* const* d_in, const int* in_sizes, int n_in,
                              void* d_out, int out_size, void* d_ws, size_t ws_size,
                              hipStream_t stream) {
    const float* F1     = (const float*)d_in[0];
    const float* F2     = (const float*)d_in[1];
    const float* W_qkv  = (const float*)d_in[2];
    const float* b_qkv  = (const float*)d_in[3];
    const float* W_proj = (const float*)d_in[4];
    const float* b_proj = (const float*)d_in[5];
    float* out = (float*)d_out;

    unsigned short* Qw  = (unsigned short*)d_ws;                 // 16 MB
    unsigned short* KVw = Qw  + (size_t)NROWS * C_DIM;           // 16 MB
    unsigned short* Xw  = KVw + (size_t)NROWS * C_DIM;           // 16 MB

    dim3 blk(256);
    dim3 gProj(4, 128);          // 512x16384 out tiles of 128x128

    gemm_bias_512<0, 1><<<gProj, blk, 0, stream>>>(F1, W_qkv, b_qkv, Qw);
    gemm_bias_512<0, 1><<<gProj, blk, 0, stream>>>(F2, W_qkv, b_qkv, KVw);
    cross_attn<<<dim3(32, 4, 8), blk, 0, stream>>>(Qw, KVw, Xw);
    gemm_bias_512<1, 0><<<gProj, blk, 0, stream>>>(Xw, W_proj, b_proj, out);
}

// Round 2
// 303.112 us; speedup vs baseline: 1.5157x; 1.5157x over previous
//
#include <hip/hip_runtime.h>
#include <math.h>

// ---------------------------------------------------------------------------
// CrossAttention: B=8, N=M=2048, C=512, H=4, D=128, shared QKV weights (K==V)
// Pipeline:
//   conv     : F1,F2 fp32 -> bf16 ws
//   wconv_t  : W fp32 [k][n] -> bf16 Wt [n][k] ws
//   gemm_bt  : Q = (F1b @ W + b)*SCALE*log2e   (bf16 ws)
//              KV = F2b @ W + b                (bf16 ws)
//   cross_attn: X = softmax2(Q KV^T) KV        (bf16 ws, fixed-max softmax)
//   gemm_bt  : out = Xb @ Wp + bp              (fp32)
// ---------------------------------------------------------------------------

typedef __attribute__((ext_vector_type(8))) short s16x8;   // 8 bf16 = 4 VGPR
typedef __attribute__((ext_vector_type(4))) float f32x4;   // MFMA acc

#define C_DIM 512
#define HDIM  128
#define NROWS 16384           // B*N = B*M
#define SCALE_Q 0.04419417382415922f
#define LOG2E   1.4426950408889634f

__device__ __forceinline__ unsigned short f2bf(float f) {
    union { float f; unsigned u; } v; v.f = f;
    unsigned r = v.u + 0x7fffu + ((v.u >> 16) & 1u);   // RNE
    return (unsigned short)(r >> 16);
}

// async global->LDS, 16B per lane; lds dest = uniform base + lane*16
__device__ __forceinline__ void async16(const void* g, void* l) {
    __builtin_amdgcn_global_load_lds(
        (const __attribute__((address_space(1))) void*)g,
        (__attribute__((address_space(3))) void*)l, 16, 0, 0);
}

// ---------------------------------------------------------------------------
// fp32 -> bf16, 8 elements/thread
// ---------------------------------------------------------------------------
__global__ __launch_bounds__(256)
void conv_bf16(const float* __restrict__ src, unsigned short* __restrict__ dst,
               int n8) {
    int i = blockIdx.x * 256 + threadIdx.x;
    if (i >= n8) return;
    float4 a = ((const float4*)src)[2 * i];
    float4 b = ((const float4*)src)[2 * i + 1];
    union { unsigned short us[8]; uint4 v; } o;
    o.us[0] = f2bf(a.x); o.us[1] = f2bf(a.y); o.us[2] = f2bf(a.z); o.us[3] = f2bf(a.w);
    o.us[4] = f2bf(b.x); o.us[5] = f2bf(b.y); o.us[6] = f2bf(b.z); o.us[7] = f2bf(b.w);
    ((uint4*)dst)[i] = o.v;
}

// ---------------------------------------------------------------------------
// W [k][n] fp32 -> Wt [n][k] bf16  (512x512), 64x64 LDS tiles
// ---------------------------------------------------------------------------
__global__ __launch_bounds__(256)
void wconv_t(const float* __restrict__ W, unsigned short* __restrict__ Wt) {
    __shared__ float t[64][65];
    const int k0 = blockIdx.y * 64, n0 = blockIdx.x * 64;
    const int c = threadIdx.x & 63, r0 = threadIdx.x >> 6;
#pragma unroll
    for (int r = r0; r < 64; r += 4)
        t[r][c] = W[(size_t)(k0 + r) * C_DIM + n0 + c];
    __syncthreads();
#pragma unroll
    for (int r = r0; r < 64; r += 4)
        Wt[(size_t)(n0 + r) * C_DIM + k0 + c] = f2bf(t[c][r]);
}

// ---------------------------------------------------------------------------
// GEMM: C[16384 x 512] = A[16384 x 512] @ Wt^T + bias, all-bf16 inputs.
// 128x128 tile, BK=32, async global_load_lds staging, unpadded LDS
// (bank-balanced for b128 frag reads). OUT_BF16: bf16 ws out, else fp32.
// oscale folded into epilogue (Q: SCALE*log2e).
// ---------------------------------------------------------------------------
template <int OUT_BF16>
__global__ __launch_bounds__(256, 2)
void gemm_bt(const unsigned short* __restrict__ A,
             const unsigned short* __restrict__ Bt,
             const float* __restrict__ bias,
             void* __restrict__ Cv, float oscale) {
    __shared__ __align__(16) unsigned short As[128][32];
    __shared__ __align__(16) unsigned short Bs[128][32];

    const int tid  = threadIdx.x;
    const int wid  = tid >> 6;
    const int lane = tid & 63;
    const int lr   = lane & 15;
    const int quad = lane >> 4;
    const int wm   = wid >> 1;
    const int wn   = wid & 1;
    const int rowBase = blockIdx.y * 128;
    const int colBase = blockIdx.x * 128;
    const int arow = lane >> 2;          // row within 16-row chunk
    const int acol = (lane & 3) * 8;     // k offset in shorts

    f32x4 acc[4][4];
#pragma unroll
    for (int i = 0; i < 4; i++)
#pragma unroll
        for (int j = 0; j < 4; j++) acc[i][j] = (f32x4)0.0f;

    for (int kt = 0; kt < 16; kt++) {
        const int k0 = kt * 32;
        __syncthreads();
#pragma unroll
        for (int c = 0; c < 2; c++) {
            const int chunk = wid * 2 + c;           // 0..7, wave-uniform
            const int row   = chunk * 16 + arow;
            async16(A  + (size_t)(rowBase + row) * C_DIM + k0 + acol, &As[chunk * 16][0]);
            async16(Bt + (size_t)(colBase + row) * C_DIM + k0 + acol, &Bs[chunk * 16][0]);
        }
        __syncthreads();   // drains vmcnt (global_load_lds) before use

        s16x8 af[4], bf[4];
#pragma unroll
        for (int i = 0; i < 4; i++)
            af[i] = *(const s16x8*)&As[wm * 64 + i * 16 + lr][quad * 8];
#pragma unroll
        for (int j = 0; j < 4; j++)
            bf[j] = *(const s16x8*)&Bs[wn * 64 + j * 16 + lr][quad * 8];
#pragma unroll
        for (int i = 0; i < 4; i++)
#pragma unroll
            for (int j = 0; j < 4; j++)
                acc[i][j] = __builtin_amdgcn_mfma_f32_16x16x32_bf16(af[i], bf[j], acc[i][j], 0, 0, 0);
    }

    // epilogue: C/D layout row = quad*4+r, col = lane&15
    float bcol[4];
#pragma unroll
    for (int j = 0; j < 4; j++)
        bcol[j] = bias[colBase + wn * 64 + j * 16 + lr];
#pragma unroll
    for (int i = 0; i < 4; i++) {
#pragma unroll
        for (int j = 0; j < 4; j++) {
            const int col = colBase + wn * 64 + j * 16 + lr;
#pragma unroll
            for (int r = 0; r < 4; r++) {
                const int row = rowBase + wm * 64 + i * 16 + quad * 4 + r;
                float v = (acc[i][j][r] + bcol[j]) * oscale;
                if (OUT_BF16)
                    ((unsigned short*)Cv)[(size_t)row * C_DIM + col] = f2bf(v);
                else
                    ((float*)Cv)[(size_t)row * C_DIM + col] = v;
            }
        }
    }
}

// ---------------------------------------------------------------------------
// Flash cross-attention v2. Grid (N/128, H, B), 256 thr, 4 waves.
// Wave: 32 queries (2 m-frags). Key tile 64. Fixed-max softmax (logits
// bounded: Q pre-scaled by SCALE*log2e, |t| < ~3): no running max, no
// rescale; l accumulated per-lane, reduced once at the end.
// ---------------------------------------------------------------------------
__global__ __launch_bounds__(256, 2)
void cross_attn(const unsigned short* __restrict__ Q,
                const unsigned short* __restrict__ KV,
                unsigned short* __restrict__ X) {
    __shared__ __align__(16) unsigned short Kt[64][136];   // [key][d] +8 pad
    __shared__ __align__(16) unsigned short Vt[128][72];   // [d][key] +8 pad
    __shared__ __align__(16) unsigned short Pl[4][32][72]; // per-wave P[q][key]

    const int tid  = threadIdx.x;
    const int wid  = tid >> 6;
    const int lane = tid & 63;
    const int lr   = lane & 15;
    const int quad = lane >> 4;
    const int b    = blockIdx.z;
    const int h    = blockIdx.y;
    const int hoff = h * HDIM;
    const size_t qrow0  = (size_t)b * 2048 + blockIdx.x * 128 + wid * 32;
    const size_t kvrow0 = (size_t)b * 2048;

    // Q fragments (already scaled by SCALE*log2e): A[m=lr][k=kk*32+quad*8+j]
    s16x8 qf[2][4];
#pragma unroll
    for (int i = 0; i < 2; i++)
#pragma unroll
        for (int kk = 0; kk < 4; kk++)
            qf[i][kk] = *(const s16x8*)(Q + (qrow0 + i * 16 + lr) * C_DIM + hoff + kk * 32 + quad * 8);

    f32x4 O[2][8];
#pragma unroll
    for (int i = 0; i < 2; i++)
#pragma unroll
        for (int dt = 0; dt < 8; dt++) O[i][dt] = (f32x4)0.0f;
    float lacc[2][4];
#pragma unroll
    for (int i = 0; i < 2; i++)
#pragma unroll
        for (int r = 0; r < 4; r++) lacc[i][r] = 0.0f;

    for (int kt = 0; kt < 32; kt++) {
        const int key0 = kt * 64;
        __syncthreads();
        // stage KV tile: lane = key; Kt b128 writes; Vt transpose (b16,
        // conflict-free: bank = (d*36 + lane/2) % 32 spans all banks 2-way)
#pragma unroll
        for (int i = 0; i < 4; i++) {
            const int dc = wid + 4 * i;   // 16B chunk along d, wave-uniform
            uint4 v = *(const uint4*)(KV + (kvrow0 + key0 + lane) * C_DIM + hoff + dc * 8);
            *(uint4*)&Kt[lane][dc * 8] = v;
            const unsigned short* e = (const unsigned short*)&v;
#pragma unroll
            for (int t = 0; t < 8; t++) Vt[dc * 8 + t][lane] = e[t];
        }
        __syncthreads();

        // S = Q KV^T : 32 MFMAs, kf shared across both i halves
        f32x4 s[2][4];
#pragma unroll
        for (int i = 0; i < 2; i++)
#pragma unroll
            for (int j = 0; j < 4; j++) s[i][j] = (f32x4)0.0f;
#pragma unroll
        for (int kk = 0; kk < 4; kk++) {
#pragma unroll
            for (int j = 0; j < 4; j++) {
                s16x8 kf = *(const s16x8*)&Kt[j * 16 + lr][kk * 32 + quad * 8];
                s[0][j] = __builtin_amdgcn_mfma_f32_16x16x32_bf16(qf[0][kk], kf, s[0][j], 0, 0, 0);
                s[1][j] = __builtin_amdgcn_mfma_f32_16x16x32_bf16(qf[1][kk], kf, s[1][j], 0, 0, 0);
            }
        }

        // fixed-max softmax: p = exp2(t), accumulate l per-lane, store P
#pragma unroll
        for (int i = 0; i < 2; i++) {
#pragma unroll
            for (int j = 0; j < 4; j++) {
#pragma unroll
                for (int r = 0; r < 4; r++) {
                    float p = exp2f(s[i][j][r]);
                    lacc[i][r] += p;
                    Pl[wid][i * 16 + quad * 4 + r][j * 16 + lr] = f2bf(p);
                }
            }
        }

        // O += P V   (wave-local LDS round-trip; DS pipe is in-order)
#pragma unroll
        for (int kk = 0; kk < 2; kk++) {
            s16x8 pa0 = *(const s16x8*)&Pl[wid][lr][kk * 32 + quad * 8];
            s16x8 pa1 = *(const s16x8*)&Pl[wid][16 + lr][kk * 32 + quad * 8];
#pragma unroll
            for (int dt = 0; dt < 8; dt++) {
                s16x8 vf = *(const s16x8*)&Vt[dt * 16 + lr][kk * 32 + quad * 8];
                O[0][dt] = __builtin_amdgcn_mfma_f32_16x16x32_bf16(pa0, vf, O[0][dt], 0, 0, 0);
                O[1][dt] = __builtin_amdgcn_mfma_f32_16x16x32_bf16(pa1, vf, O[1][dt], 0, 0, 0);
            }
        }
    }

    // final l reduction (16 lanes of the quad-row group) + write X
#pragma unroll
    for (int i = 0; i < 2; i++) {
#pragma unroll
        for (int r = 0; r < 4; r++) {
            float l = lacc[i][r];
#pragma unroll
            for (int off = 1; off < 16; off <<= 1)
                l += __shfl_xor(l, off);
            const float inv = 1.0f / l;
            const size_t row = (qrow0 + i * 16 + quad * 4 + r) * C_DIM + hoff;
#pragma unroll
            for (int dt = 0; dt < 8; dt++)
                X[row + dt * 16 + lr] = f2bf(O[i][dt][r] * inv);
        }
    }
}

// ---------------------------------------------------------------------------
extern "C" void kernel_launch(void* const* d_in, const int* in_sizes, int n_in,
                              void* d_out, int out_size, void* d_ws, size_t ws_size,
                              hipStream_t stream) {
    const float* F1     = (const float*)d_in[0];
    const float* F2     = (const float*)d_in[1];
    const float* W_qkv  = (const float*)d_in[2];
    const float* b_qkv  = (const float*)d_in[3];
    const float* W_proj = (const float*)d_in[4];
    const float* b_proj = (const float*)d_in[5];
    float* out = (float*)d_out;

    const size_t NC = (size_t)NROWS * C_DIM;       // 8.4M elems
    unsigned short* F1b = (unsigned short*)d_ws;   // 16MB (aliased by Xw later)
    unsigned short* F2b = F1b + NC;                // 16MB
    unsigned short* Qw  = F2b + NC;                // 16MB
    unsigned short* KVw = Qw  + NC;                // 16MB
    unsigned short* Wqt = KVw + NC;                // 0.5MB
    unsigned short* Wpt = Wqt + C_DIM * C_DIM;     // 0.5MB
    unsigned short* Xw  = F1b;                     // alias: F1b dead after gemm1

    dim3 blk(256);
    dim3 gProj(4, 128);

    conv_bf16<<<dim3(NC / 8 / 256), blk, 0, stream>>>(F1, F1b, (int)(NC / 8));
    conv_bf16<<<dim3(NC / 8 / 256), blk, 0, stream>>>(F2, F2b, (int)(NC / 8));
    wconv_t<<<dim3(8, 8), blk, 0, stream>>>(W_qkv, Wqt);
    wconv_t<<<dim3(8, 8), blk, 0, stream>>>(W_proj, Wpt);

    gemm_bt<1><<<gProj, blk, 0, stream>>>(F1b, Wqt, b_qkv, Qw, SCALE_Q * LOG2E);
    gemm_bt<1><<<gProj, blk, 0, stream>>>(F2b, Wqt, b_qkv, KVw, 1.0f);
    cross_attn<<<dim3(16, 4, 8), blk, 0, stream>>>(Qw, KVw, Xw);
    gemm_bt<0><<<gProj, blk, 0, stream>>>(Xw, Wpt, b_proj, out, 1.0f);
}

// Round 3
// 300.094 us; speedup vs baseline: 1.5310x; 1.0101x over previous
//
#include <hip/hip_runtime.h>
#include <math.h>

// ---------------------------------------------------------------------------
// CrossAttention: B=8, N=M=2048, C=512, H=4, D=128, shared QKV weights (K==V)
// Pipeline:
//   conv     : F1,F2 fp32 -> bf16 ws
//   wconv_t  : W fp32 [k][n] -> bf16 Wt [n][k] ws
//   gemm_bt  : Q = (F1b @ W + b)*SCALE*log2e   (bf16 ws)
//              KV = F2b @ W + b                (bf16 ws)
//   cross_attn: X = softmax2(Q KV^T) KV        (bf16 ws, fixed-max softmax)
//   gemm_bt  : out = Xb @ Wp + bp              (fp32)
// ---------------------------------------------------------------------------

typedef __attribute__((ext_vector_type(8))) short s16x8;   // 8 bf16 = 4 VGPR
typedef __attribute__((ext_vector_type(4))) float f32x4;   // MFMA acc

#define C_DIM 512
#define HDIM  128
#define NROWS 16384           // B*N = B*M
#define SCALE_Q 0.04419417382415922f
#define LOG2E   1.4426950408889634f

__device__ __forceinline__ unsigned short f2bf(float f) {
    union { float f; unsigned u; } v; v.f = f;
    unsigned r = v.u + 0x7fffu + ((v.u >> 16) & 1u);   // RNE
    return (unsigned short)(r >> 16);
}

// async global->LDS, 16B per lane; lds dest = uniform base + lane*16
__device__ __forceinline__ void async16(const void* g, void* l) {
    __builtin_amdgcn_global_load_lds(
        (const __attribute__((address_space(1))) void*)g,
        (__attribute__((address_space(3))) void*)l, 16, 0, 0);
}

// ---------------------------------------------------------------------------
// fp32 -> bf16, 8 elements/thread
// ---------------------------------------------------------------------------
__global__ __launch_bounds__(256)
void conv_bf16(const float* __restrict__ src, unsigned short* __restrict__ dst,
               int n8) {
    int i = blockIdx.x * 256 + threadIdx.x;
    if (i >= n8) return;
    float4 a = ((const float4*)src)[2 * i];
    float4 b = ((const float4*)src)[2 * i + 1];
    union { unsigned short us[8]; uint4 v; } o;
    o.us[0] = f2bf(a.x); o.us[1] = f2bf(a.y); o.us[2] = f2bf(a.z); o.us[3] = f2bf(a.w);
    o.us[4] = f2bf(b.x); o.us[5] = f2bf(b.y); o.us[6] = f2bf(b.z); o.us[7] = f2bf(b.w);
    ((uint4*)dst)[i] = o.v;
}

// ---------------------------------------------------------------------------
// W [k][n] fp32 -> Wt [n][k] bf16  (512x512), 64x64 LDS tiles
// ---------------------------------------------------------------------------
__global__ __launch_bounds__(256)
void wconv_t(const float* __restrict__ W, unsigned short* __restrict__ Wt) {
    __shared__ float t[64][65];
    const int k0 = blockIdx.y * 64, n0 = blockIdx.x * 64;
    const int c = threadIdx.x & 63, r0 = threadIdx.x >> 6;
#pragma unroll
    for (int r = r0; r < 64; r += 4)
        t[r][c] = W[(size_t)(k0 + r) * C_DIM + n0 + c];
    __syncthreads();
#pragma unroll
    for (int r = r0; r < 64; r += 4)
        Wt[(size_t)(n0 + r) * C_DIM + k0 + c] = f2bf(t[c][r]);
}

// ---------------------------------------------------------------------------
// GEMM: C[16384 x 512] = A[16384 x 512] @ Wt^T + bias, all-bf16 inputs.
// 128x128 tile, BK=32, async global_load_lds staging.
// XOR source-swizzle: LDS[row][kc] holds global chunk kc ^ ((row>>1)&3);
// frag reads at chunk quad ^ ((lr>>1)&3) -> 2-way banks (free) instead of
// the 8-way conflict of the naive [128][32] layout.
// ---------------------------------------------------------------------------
template <int OUT_BF16>
__global__ __launch_bounds__(256, 2)
void gemm_bt(const unsigned short* __restrict__ A,
             const unsigned short* __restrict__ Bt,
             const float* __restrict__ bias,
             void* __restrict__ Cv, float oscale) {
    __shared__ __align__(16) unsigned short As[128][32];
    __shared__ __align__(16) unsigned short Bs[128][32];

    const int tid  = threadIdx.x;
    const int wid  = tid >> 6;
    const int lane = tid & 63;
    const int lr   = lane & 15;
    const int quad = lane >> 4;
    const int wm   = wid >> 1;
    const int wn   = wid & 1;
    const int rowBase = blockIdx.y * 128;
    const int colBase = blockIdx.x * 128;
    const int arow = lane >> 2;                       // row within 16-row chunk
    const int kcs  = ((lane & 3) ^ ((lane >> 3) & 3)) * 8;  // swizzled src k
    const int fsw  = (quad ^ ((lr >> 1) & 3)) * 8;    // swizzled frag chunk

    f32x4 acc[4][4];
#pragma unroll
    for (int i = 0; i < 4; i++)
#pragma unroll
        for (int j = 0; j < 4; j++) acc[i][j] = (f32x4)0.0f;

    for (int kt = 0; kt < 16; kt++) {
        const int k0 = kt * 32;
        __syncthreads();
#pragma unroll
        for (int c = 0; c < 2; c++) {
            const int chunk = wid * 2 + c;           // 0..7, wave-uniform
            const int row   = chunk * 16 + arow;
            async16(A  + (size_t)(rowBase + row) * C_DIM + k0 + kcs, &As[chunk * 16][0]);
            async16(Bt + (size_t)(colBase + row) * C_DIM + k0 + kcs, &Bs[chunk * 16][0]);
        }
        __syncthreads();   // drains vmcnt (global_load_lds) before use

        s16x8 af[4], bf[4];
#pragma unroll
        for (int i = 0; i < 4; i++)
            af[i] = *(const s16x8*)&As[wm * 64 + i * 16 + lr][fsw];
#pragma unroll
        for (int j = 0; j < 4; j++)
            bf[j] = *(const s16x8*)&Bs[wn * 64 + j * 16 + lr][fsw];
#pragma unroll
        for (int i = 0; i < 4; i++)
#pragma unroll
            for (int j = 0; j < 4; j++)
                acc[i][j] = __builtin_amdgcn_mfma_f32_16x16x32_bf16(af[i], bf[j], acc[i][j], 0, 0, 0);
    }

    // epilogue: C/D layout row = quad*4+r, col = lane&15
    float bcol[4];
#pragma unroll
    for (int j = 0; j < 4; j++)
        bcol[j] = bias[colBase + wn * 64 + j * 16 + lr];
#pragma unroll
    for (int i = 0; i < 4; i++) {
#pragma unroll
        for (int j = 0; j < 4; j++) {
            const int col = colBase + wn * 64 + j * 16 + lr;
#pragma unroll
            for (int r = 0; r < 4; r++) {
                const int row = rowBase + wm * 64 + i * 16 + quad * 4 + r;
                float v = (acc[i][j][r] + bcol[j]) * oscale;
                if (OUT_BF16)
                    ((unsigned short*)Cv)[(size_t)row * C_DIM + col] = f2bf(v);
                else
                    ((float*)Cv)[(size_t)row * C_DIM + col] = v;
            }
        }
    }
}

// ---------------------------------------------------------------------------
// Flash cross-attention v3. Grid (N/128, H, B), 256 thr, 4 waves, 32 q/wave.
// Key remap: S-tile column n of MFMA j <-> key 4n+j. Lane l stages key
// kappa(l) = (l&15)*4 + (l>>4) into Kt row l, so row j*16+lr holds key
// 4lr+j (kf indexing unchanged) and each lane's 4 probs (j=0..3) are
// CONTIGUOUS keys -> single b64 Pl write (was 32 4-way-conflicted b16).
// Fixed-max softmax (Q pre-scaled by SCALE*log2e).
// ---------------------------------------------------------------------------
__global__ __launch_bounds__(256, 2)
void cross_attn(const unsigned short* __restrict__ Q,
                const unsigned short* __restrict__ KV,
                unsigned short* __restrict__ X) {
    __shared__ __align__(16) unsigned short Kt[64][136];   // [row=pi(key)][d]
    __shared__ __align__(16) unsigned short Vt[128][72];   // [d][key] +8 pad
    __shared__ __align__(16) unsigned short Pl[4][32][72]; // per-wave P[q][key]

    const int tid  = threadIdx.x;
    const int wid  = tid >> 6;
    const int lane = tid & 63;
    const int lr   = lane & 15;
    const int quad = lane >> 4;
    const int b    = blockIdx.z;
    const int h    = blockIdx.y;
    const int hoff = h * HDIM;
    const int kap  = lr * 4 + quad;            // kappa(lane): key this lane stages
    const size_t qrow0  = (size_t)b * 2048 + blockIdx.x * 128 + wid * 32;
    const size_t kvrow0 = (size_t)b * 2048;

    // Q fragments (already scaled by SCALE*log2e): A[m=lr][k=kk*32+quad*8+j]
    s16x8 qf[2][4];
#pragma unroll
    for (int i = 0; i < 2; i++)
#pragma unroll
        for (int kk = 0; kk < 4; kk++)
            qf[i][kk] = *(const s16x8*)(Q + (qrow0 + i * 16 + lr) * C_DIM + hoff + kk * 32 + quad * 8);

    f32x4 O[2][8];
#pragma unroll
    for (int i = 0; i < 2; i++)
#pragma unroll
        for (int dt = 0; dt < 8; dt++) O[i][dt] = (f32x4)0.0f;
    float lacc[2][4];
#pragma unroll
    for (int i = 0; i < 2; i++)
#pragma unroll
        for (int r = 0; r < 4; r++) lacc[i][r] = 0.0f;

    for (int kt = 0; kt < 32; kt++) {
        const int key0 = kt * 64;
        __syncthreads();
        // stage KV tile: lane stages key kappa(lane) into Kt row lane;
        // Vt[d][key] at the key's natural position (2-way banks, free).
#pragma unroll
        for (int i = 0; i < 4; i++) {
            const int dc = wid + 4 * i;   // 16B chunk along d, wave-uniform
            uint4 v = *(const uint4*)(KV + (kvrow0 + key0 + kap) * C_DIM + hoff + dc * 8);
            *(uint4*)&Kt[lane][dc * 8] = v;
            const unsigned short* e = (const unsigned short*)&v;
#pragma unroll
            for (int t = 0; t < 8; t++) Vt[dc * 8 + t][kap] = e[t];
        }
        __syncthreads();

        // S = Q KV^T : 32 MFMAs; MFMA j covers keys 4n+j (n = column)
        f32x4 s[2][4];
#pragma unroll
        for (int i = 0; i < 2; i++)
#pragma unroll
            for (int j = 0; j < 4; j++) s[i][j] = (f32x4)0.0f;
#pragma unroll
        for (int kk = 0; kk < 4; kk++) {
#pragma unroll
            for (int j = 0; j < 4; j++) {
                s16x8 kf = *(const s16x8*)&Kt[j * 16 + lr][kk * 32 + quad * 8];
                s[0][j] = __builtin_amdgcn_mfma_f32_16x16x32_bf16(qf[0][kk], kf, s[0][j], 0, 0, 0);
                s[1][j] = __builtin_amdgcn_mfma_f32_16x16x32_bf16(qf[1][kk], kf, s[1][j], 0, 0, 0);
            }
        }

        // fixed-max softmax + packed b64 P write (keys 4lr..4lr+3)
#pragma unroll
        for (int i = 0; i < 2; i++) {
#pragma unroll
            for (int r = 0; r < 4; r++) {
                float p0 = exp2f(s[i][0][r]);
                float p1 = exp2f(s[i][1][r]);
                float p2 = exp2f(s[i][2][r]);
                float p3 = exp2f(s[i][3][r]);
                lacc[i][r] += (p0 + p1) + (p2 + p3);
                uint2 pk;
                pk.x = (unsigned)f2bf(p0) | ((unsigned)f2bf(p1) << 16);
                pk.y = (unsigned)f2bf(p2) | ((unsigned)f2bf(p3) << 16);
                *(uint2*)&Pl[wid][i * 16 + quad * 4 + r][4 * lr] = pk;
            }
        }

        // O += P V   (wave-local LDS round-trip; DS pipe is in-order)
#pragma unroll
        for (int kk = 0; kk < 2; kk++) {
            s16x8 pa0 = *(const s16x8*)&Pl[wid][lr][kk * 32 + quad * 8];
            s16x8 pa1 = *(const s16x8*)&Pl[wid][16 + lr][kk * 32 + quad * 8];
#pragma unroll
            for (int dt = 0; dt < 8; dt++) {
                s16x8 vf = *(const s16x8*)&Vt[dt * 16 + lr][kk * 32 + quad * 8];
                O[0][dt] = __builtin_amdgcn_mfma_f32_16x16x32_bf16(pa0, vf, O[0][dt], 0, 0, 0);
                O[1][dt] = __builtin_amdgcn_mfma_f32_16x16x32_bf16(pa1, vf, O[1][dt], 0, 0, 0);
            }
        }
    }

    // final l reduction (16 lanes of the quad-row group) + write X
#pragma unroll
    for (int i = 0; i < 2; i++) {
#pragma unroll
        for (int r = 0; r < 4; r++) {
            float l = lacc[i][r];
#pragma unroll
            for (int off = 1; off < 16; off <<= 1)
                l += __shfl_xor(l, off);
            const float inv = 1.0f / l;
            const size_t row = (qrow0 + i * 16 + quad * 4 + r) * C_DIM + hoff;
#pragma unroll
            for (int dt = 0; dt < 8; dt++)
                X[row + dt * 16 + lr] = f2bf(O[i][dt][r] * inv);
        }
    }
}

// ---------------------------------------------------------------------------
extern "C" void kernel_launch(void* const* d_in, const int* in_sizes, int n_in,
                              void* d_out, int out_size, void* d_ws, size_t ws_size,
                              hipStream_t stream) {
    const float* F1     = (const float*)d_in[0];
    const float* F2     = (const float*)d_in[1];
    const float* W_qkv  = (const float*)d_in[2];
    const float* b_qkv  = (const float*)d_in[3];
    const float* W_proj = (const float*)d_in[4];
    const float* b_proj = (const float*)d_in[5];
    float* out = (float*)d_out;

    const size_t NC = (size_t)NROWS * C_DIM;       // 8.4M elems
    unsigned short* F1b = (unsigned short*)d_ws;   // 16MB (aliased by Xw later)
    unsigned short* F2b = F1b + NC;                // 16MB
    unsigned short* Qw  = F2b + NC;                // 16MB
    unsigned short* KVw = Qw  + NC;                // 16MB
    unsigned short* Wqt = KVw + NC;                // 0.5MB
    unsigned short* Wpt = Wqt + C_DIM * C_DIM;     // 0.5MB
    unsigned short* Xw  = F1b;                     // alias: F1b dead after gemm1

    dim3 blk(256);
    dim3 gProj(4, 128);

    conv_bf16<<<dim3(NC / 8 / 256), blk, 0, stream>>>(F1, F1b, (int)(NC / 8));
    conv_bf16<<<dim3(NC / 8 / 256), blk, 0, stream>>>(F2, F2b, (int)(NC / 8));
    wconv_t<<<dim3(8, 8), blk, 0, stream>>>(W_qkv, Wqt);
    wconv_t<<<dim3(8, 8), blk, 0, stream>>>(W_proj, Wpt);

    gemm_bt<1><<<gProj, blk, 0, stream>>>(F1b, Wqt, b_qkv, Qw, SCALE_Q * LOG2E);
    gemm_bt<1><<<gProj, blk, 0, stream>>>(F2b, Wqt, b_qkv, KVw, 1.0f);
    cross_attn<<<dim3(16, 4, 8), blk, 0, stream>>>(Qw, KVw, Xw);
    gemm_bt<0><<<gProj, blk, 0, stream>>>(Xw, Wpt, b_proj, out, 1.0f);
}

// Round 4
// 282.532 us; speedup vs baseline: 1.6262x; 1.0622x over previous
//
#include <hip/hip_runtime.h>
#include <math.h>

// ---------------------------------------------------------------------------
// CrossAttention: B=8, N=M=2048, C=512, H=4, D=128, shared QKV weights (K==V)
// Pipeline (5 dispatches):
//   conv2    : F1,F2 fp32 -> bf16 ws (one dispatch)
//   wconv2   : W_qkv,W_proj fp32 [k][n] -> bf16 [n][k] ws (one dispatch)
//   gemm_bt  : [Q;KV] = [F1b;F2b] @ W + b  (fused, per-half scale, bf16 ws)
//   cross_attn: X = softmax2(Q KV^T) KV    (bf16 ws, fixed-max softmax)
//   gemm_bt  : out = Xb @ Wp + bp          (fp32)
// ---------------------------------------------------------------------------

typedef __attribute__((ext_vector_type(8))) short s16x8;   // 8 bf16 = 4 VGPR
typedef __attribute__((ext_vector_type(4))) float f32x4;   // MFMA acc

#define C_DIM 512
#define HDIM  128
#define NROWS 16384           // B*N = B*M
#define SCALE_Q 0.04419417382415922f
#define LOG2E   1.4426950408889634f

__device__ __forceinline__ unsigned short f2bf(float f) {
    union { float f; unsigned u; } v; v.f = f;
    unsigned r = v.u + 0x7fffu + ((v.u >> 16) & 1u);   // RNE
    return (unsigned short)(r >> 16);
}

// async global->LDS, 16B per lane; lds dest = uniform base + lane*16
__device__ __forceinline__ void async16(const void* g, void* l) {
    __builtin_amdgcn_global_load_lds(
        (const __attribute__((address_space(1))) void*)g,
        (__attribute__((address_space(3))) void*)l, 16, 0, 0);
}

// ---------------------------------------------------------------------------
// fp32 -> bf16, 8 elements/thread; y-dim selects (src,dst) pair
// ---------------------------------------------------------------------------
__global__ __launch_bounds__(256)
void conv_bf16_2(const float* __restrict__ s0, const float* __restrict__ s1,
                 unsigned short* __restrict__ d0, unsigned short* __restrict__ d1,
                 int n8) {
    const float* src = blockIdx.y ? s1 : s0;
    unsigned short* dst = blockIdx.y ? d1 : d0;
    int i = blockIdx.x * 256 + threadIdx.x;
    if (i >= n8) return;
    float4 a = ((const float4*)src)[2 * i];
    float4 b = ((const float4*)src)[2 * i + 1];
    union { unsigned short us[8]; uint4 v; } o;
    o.us[0] = f2bf(a.x); o.us[1] = f2bf(a.y); o.us[2] = f2bf(a.z); o.us[3] = f2bf(a.w);
    o.us[4] = f2bf(b.x); o.us[5] = f2bf(b.y); o.us[6] = f2bf(b.z); o.us[7] = f2bf(b.w);
    ((uint4*)dst)[i] = o.v;
}

// ---------------------------------------------------------------------------
// W [k][n] fp32 -> Wt [n][k] bf16 (512x512), 64x64 tiles; z selects pair
// ---------------------------------------------------------------------------
__global__ __launch_bounds__(256)
void wconv_t2(const float* __restrict__ W0, const float* __restrict__ W1,
              unsigned short* __restrict__ T0, unsigned short* __restrict__ T1) {
    const float* W = blockIdx.z ? W1 : W0;
    unsigned short* Wt = blockIdx.z ? T1 : T0;
    __shared__ float t[64][65];
    const int k0 = blockIdx.y * 64, n0 = blockIdx.x * 64;
    const int c = threadIdx.x & 63, r0 = threadIdx.x >> 6;
#pragma unroll
    for (int r = r0; r < 64; r += 4)
        t[r][c] = W[(size_t)(k0 + r) * C_DIM + n0 + c];
    __syncthreads();
#pragma unroll
    for (int r = r0; r < 64; r += 4)
        Wt[(size_t)(n0 + r) * C_DIM + k0 + c] = f2bf(t[c][r]);
}

// ---------------------------------------------------------------------------
// GEMM: C[rows x 512] = A[rows x 512] @ Wt^T + bias, all-bf16 inputs.
// 128x128 tile, BK=64 (8 k-iters), async global_load_lds staging.
// LDS rows are 64 shorts (32 dwords == 0 mod 32): XOR chunk swizzle
// (position = chunk ^ (row&7)) applied at the GLOBAL source so frag reads
// sit at the b128 bank floor. Epilogue scale oscTop for rows < topRows
// (fused Q/KV projection), else 1.
// ---------------------------------------------------------------------------
template <int OUT_BF16>
__global__ __launch_bounds__(256, 3)
void gemm_bt(const unsigned short* __restrict__ A,
             const unsigned short* __restrict__ Bt,
             const float* __restrict__ bias,
             void* __restrict__ Cv, float oscTop, int topRows) {
    __shared__ __align__(16) unsigned short As[128][64];
    __shared__ __align__(16) unsigned short Bs[128][64];

    const int tid  = threadIdx.x;
    const int wid  = tid >> 6;
    const int lane = tid & 63;
    const int lr   = lane & 15;
    const int quad = lane >> 4;
    const int wm   = wid >> 1;
    const int wn   = wid & 1;
    const int rowBase = blockIdx.y * 128;
    const int colBase = blockIdx.x * 128;
    // staging: per async16, lane covers row +(lane>>3), chunk pos lane&7,
    // global chunk c = (lane&7) ^ ((lane>>3)&7)
    const int srow = lane >> 3;
    const int soff = srow * C_DIM + (((lane & 7) ^ (srow & 7)) * 8);
    const float osc = (rowBase < topRows) ? oscTop : 1.0f;

    f32x4 acc[4][4];
#pragma unroll
    for (int i = 0; i < 4; i++)
#pragma unroll
        for (int j = 0; j < 4; j++) acc[i][j] = (f32x4)0.0f;

    for (int kt = 0; kt < 8; kt++) {
        const int k0 = kt * 64;
        __syncthreads();
#pragma unroll
        for (int i = 0; i < 4; i++) {
            const int R = wid * 32 + i * 8;            // wave-uniform row block
            async16(A  + (size_t)(rowBase + R) * C_DIM + k0 + soff, &As[R][0]);
            async16(Bt + (size_t)(colBase + R) * C_DIM + k0 + soff, &Bs[R][0]);
        }
        __syncthreads();   // drains vmcnt before frag reads

#pragma unroll
        for (int s = 0; s < 2; s++) {
            s16x8 af[4], bf[4];
#pragma unroll
            for (int i = 0; i < 4; i++)
                af[i] = *(const s16x8*)&As[wm * 64 + i * 16 + lr][((s * 4 + quad) ^ (lr & 7)) * 8];
#pragma unroll
            for (int j = 0; j < 4; j++)
                bf[j] = *(const s16x8*)&Bs[wn * 64 + j * 16 + lr][((s * 4 + quad) ^ (lr & 7)) * 8];
#pragma unroll
            for (int i = 0; i < 4; i++)
#pragma unroll
                for (int j = 0; j < 4; j++)
                    acc[i][j] = __builtin_amdgcn_mfma_f32_16x16x32_bf16(af[i], bf[j], acc[i][j], 0, 0, 0);
        }
    }

    // epilogue: C/D layout row = quad*4+r, col = lane&15
    float bcol[4];
#pragma unroll
    for (int j = 0; j < 4; j++)
        bcol[j] = bias[colBase + wn * 64 + j * 16 + lr];
#pragma unroll
    for (int i = 0; i < 4; i++) {
#pragma unroll
        for (int j = 0; j < 4; j++) {
            const int col = colBase + wn * 64 + j * 16 + lr;
#pragma unroll
            for (int r = 0; r < 4; r++) {
                const int row = rowBase + wm * 64 + i * 16 + quad * 4 + r;
                float v = (acc[i][j][r] + bcol[j]) * osc;
                if (OUT_BF16)
                    ((unsigned short*)Cv)[(size_t)row * C_DIM + col] = f2bf(v);
                else
                    ((float*)Cv)[(size_t)row * C_DIM + col] = v;
            }
        }
    }
}

// ---------------------------------------------------------------------------
// Flash cross-attention v4. Grid (N/128, H, B), 256 thr, 4 waves, 32 q/wave.
// Key remap: S column n of MFMA j <-> key 4n+j; lane stages key
// kappa = 4*(lane&15)+(lane>>4) so P probs pack into one b64 write.
// Kt is [64][128] (unpadded) with XOR chunk swizzle pos = chunk ^ (row&7)
// -> LDS 53248 B -> 3 blocks/CU. Fixed-max softmax (Q pre-scaled).
// ---------------------------------------------------------------------------
__global__ __launch_bounds__(256, 3)
void cross_attn(const unsigned short* __restrict__ Q,
                const unsigned short* __restrict__ KV,
                unsigned short* __restrict__ X) {
    __shared__ __align__(16) unsigned short Kt[64][128];   // [row][d] swizzled
    __shared__ __align__(16) unsigned short Vt[128][72];   // [d][key] +8 pad
    __shared__ __align__(16) unsigned short Pl[4][32][72]; // per-wave P[q][key]

    const int tid  = threadIdx.x;
    const int wid  = tid >> 6;
    const int lane = tid & 63;
    const int lr   = lane & 15;
    const int quad = lane >> 4;
    const int b    = blockIdx.z;
    const int h    = blockIdx.y;
    const int hoff = h * HDIM;
    const int kap  = lr * 4 + quad;            // key this lane stages
    const int l7   = lane & 7;
    const size_t qrow0  = (size_t)b * 2048 + blockIdx.x * 128 + wid * 32;
    const size_t kvrow0 = (size_t)b * 2048;

    // Q fragments (pre-scaled by SCALE*log2e): A[m=lr][k=kk*32+quad*8+j]
    s16x8 qf[2][4];
#pragma unroll
    for (int i = 0; i < 2; i++)
#pragma unroll
        for (int kk = 0; kk < 4; kk++)
            qf[i][kk] = *(const s16x8*)(Q + (qrow0 + i * 16 + lr) * C_DIM + hoff + kk * 32 + quad * 8);

    f32x4 O[2][8];
#pragma unroll
    for (int i = 0; i < 2; i++)
#pragma unroll
        for (int dt = 0; dt < 8; dt++) O[i][dt] = (f32x4)0.0f;
    float lacc[2][4];
#pragma unroll
    for (int i = 0; i < 2; i++)
#pragma unroll
        for (int r = 0; r < 4; r++) lacc[i][r] = 0.0f;

    for (int kt = 0; kt < 32; kt++) {
        const int key0 = kt * 64;
        __syncthreads();
        // stage KV tile: lane stages key kappa into Kt row lane (chunk pos
        // dc ^ (lane&7)); Vt[d][key] b16 transpose (2-way banks, free).
#pragma unroll
        for (int i = 0; i < 4; i++) {
            const int dc = wid + 4 * i;   // 16B chunk along d, wave-uniform
            uint4 v = *(const uint4*)(KV + (kvrow0 + key0 + kap) * C_DIM + hoff + dc * 8);
            *(uint4*)&Kt[lane][(dc ^ l7) * 8] = v;
            const unsigned short* e = (const unsigned short*)&v;
#pragma unroll
            for (int t = 0; t < 8; t++) Vt[dc * 8 + t][kap] = e[t];
        }
        __syncthreads();

        // S = Q KV^T : 32 MFMAs; MFMA j covers keys 4n+j
        f32x4 s[2][4];
#pragma unroll
        for (int i = 0; i < 2; i++)
#pragma unroll
            for (int j = 0; j < 4; j++) s[i][j] = (f32x4)0.0f;
#pragma unroll
        for (int kk = 0; kk < 4; kk++) {
#pragma unroll
            for (int j = 0; j < 4; j++) {
                s16x8 kf = *(const s16x8*)&Kt[j * 16 + lr][((kk * 4 + quad) ^ (lr & 7)) * 8];
                s[0][j] = __builtin_amdgcn_mfma_f32_16x16x32_bf16(qf[0][kk], kf, s[0][j], 0, 0, 0);
                s[1][j] = __builtin_amdgcn_mfma_f32_16x16x32_bf16(qf[1][kk], kf, s[1][j], 0, 0, 0);
            }
        }

        // fixed-max softmax + packed b64 P write (keys 4lr..4lr+3)
#pragma unroll
        for (int i = 0; i < 2; i++) {
#pragma unroll
            for (int r = 0; r < 4; r++) {
                float p0 = exp2f(s[i][0][r]);
                float p1 = exp2f(s[i][1][r]);
                float p2 = exp2f(s[i][2][r]);
                float p3 = exp2f(s[i][3][r]);
                lacc[i][r] += (p0 + p1) + (p2 + p3);
                uint2 pk;
                pk.x = (unsigned)f2bf(p0) | ((unsigned)f2bf(p1) << 16);
                pk.y = (unsigned)f2bf(p2) | ((unsigned)f2bf(p3) << 16);
                *(uint2*)&Pl[wid][i * 16 + quad * 4 + r][4 * lr] = pk;
            }
        }

        // O += P V   (wave-local LDS round-trip; DS pipe is in-order)
#pragma unroll
        for (int kk = 0; kk < 2; kk++) {
            s16x8 pa0 = *(const s16x8*)&Pl[wid][lr][kk * 32 + quad * 8];
            s16x8 pa1 = *(const s16x8*)&Pl[wid][16 + lr][kk * 32 + quad * 8];
#pragma unroll
            for (int dt = 0; dt < 8; dt++) {
                s16x8 vf = *(const s16x8*)&Vt[dt * 16 + lr][kk * 32 + quad * 8];
                O[0][dt] = __builtin_amdgcn_mfma_f32_16x16x32_bf16(pa0, vf, O[0][dt], 0, 0, 0);
                O[1][dt] = __builtin_amdgcn_mfma_f32_16x16x32_bf16(pa1, vf, O[1][dt], 0, 0, 0);
            }
        }
    }

    // final l reduction (16 lanes of the quad-row group) + write X
#pragma unroll
    for (int i = 0; i < 2; i++) {
#pragma unroll
        for (int r = 0; r < 4; r++) {
            float l = lacc[i][r];
#pragma unroll
            for (int off = 1; off < 16; off <<= 1)
                l += __shfl_xor(l, off);
            const float inv = 1.0f / l;
            const size_t row = (qrow0 + i * 16 + quad * 4 + r) * C_DIM + hoff;
#pragma unroll
            for (int dt = 0; dt < 8; dt++)
                X[row + dt * 16 + lr] = f2bf(O[i][dt][r] * inv);
        }
    }
}

// ---------------------------------------------------------------------------
extern "C" void kernel_launch(void* const* d_in, const int* in_sizes, int n_in,
                              void* d_out, int out_size, void* d_ws, size_t ws_size,
                              hipStream_t stream) {
    const float* F1     = (const float*)d_in[0];
    const float* F2     = (const float*)d_in[1];
    const float* W_qkv  = (const float*)d_in[2];
    const float* b_qkv  = (const float*)d_in[3];
    const float* W_proj = (const float*)d_in[4];
    const float* b_proj = (const float*)d_in[5];
    float* out = (float*)d_out;

    const size_t NC = (size_t)NROWS * C_DIM;       // 8.4M elems
    unsigned short* F1b = (unsigned short*)d_ws;   // 16MB (F1b||F2b contiguous)
    unsigned short* F2b = F1b + NC;                // 16MB
    unsigned short* Qw  = F2b + NC;                // 16MB (Qw||KVw contiguous)
    unsigned short* KVw = Qw  + NC;                // 16MB
    unsigned short* Wqt = KVw + NC;                // 0.5MB
    unsigned short* Wpt = Wqt + C_DIM * C_DIM;     // 0.5MB
    unsigned short* Xw  = F1b;                     // alias: F1b dead after QKV gemm

    dim3 blk(256);

    conv_bf16_2<<<dim3(NC / 8 / 256, 2), blk, 0, stream>>>(F1, F2, F1b, F2b, (int)(NC / 8));
    wconv_t2<<<dim3(8, 8, 2), blk, 0, stream>>>(W_qkv, W_proj, Wqt, Wpt);

    // fused Q+KV projection: 32768 rows, top half scaled by SCALE*log2e
    gemm_bt<1><<<dim3(4, 256), blk, 0, stream>>>(F1b, Wqt, b_qkv, Qw, SCALE_Q * LOG2E, NROWS);
    cross_attn<<<dim3(16, 4, 8), blk, 0, stream>>>(Qw, KVw, Xw);
    gemm_bt<0><<<dim3(4, 128), blk, 0, stream>>>(Xw, Wpt, b_proj, out, 1.0f, 0);
}